// Round 11
// baseline (495.612 us; speedup 1.0000x reference)
//
#include <hip/hip_runtime.h>
#include <hip/hip_cooperative_groups.h>

namespace cg = cooperative_groups;

// Problem constants (fixed by the reference)
#define NN 8192
#define EE 262144
#define CC 64
#define STRIDE 96   // bucket slots/row; Poisson(32) max ~66, P(>96) ~ 1e-19

typedef unsigned long long u64;

// ============================ FUSED (cooperative) ============================
// 1024 blocks x 256 threads = 4096 waves; each wave owns rows {r, r+4096}.
// Needs only 4 blocks/CU co-residency (R7 evidence: this config launched).
// All gather loops use WAVE-UNIFORM trip counts so every __shfl executes with
// all 64 lanes active (R7/R8 bug: per-lane loop exit masked shfl source lanes
// in the tail iteration; lanes beyond k hold w=0 so extra iterations add 0).
__global__ __launch_bounds__(256, 4) void k_fused(
        const float* __restrict__ x, const int* __restrict__ ei,
        const float* __restrict__ ew, const float* __restrict__ W,
        const float* __restrict__ adw, const float* __restrict__ bias,
        float* __restrict__ out, int* __restrict__ cnt, u64* __restrict__ ecw,
        float* __restrict__ dinv, float* __restrict__ tx1) {
    cg::grid_group grid = cg::this_grid();
    __shared__ u64 sbuf[4][2][STRIDE];   // 6 KB: dedup staging + epilogue reuse

    int tid  = threadIdx.x;
    int gid  = blockIdx.x * 256 + tid;   // 0..EE-1 exactly
    int lane = tid & 63;
    int rloc = tid >> 6;

    // ---- A: zero per-row counters
    if (gid < NN) cnt[gid] = 0;
    grid.sync();

    // ---- B: bucket fill. hi32 = (e<<13)|col (max == last write per col)
    {
        int r = ei[gid];
        int c = ei[EE + gid];
        int pos = atomicAdd(&cnt[r], 1);
        if (pos < STRIDE) {
            u64 v = ((u64)(((unsigned)gid << 13) | (unsigned)c) << 32)
                  | (u64)__float_as_uint(ew[gid]);
            ecw[r * STRIDE + pos] = v;
        }
    }
    grid.sync();

    // ---- C: per-row dedup in LDS; edges stay in REGISTERS afterwards
    float sig = 1.0f / (1.0f + expf(-adw[0]));
    int rows[2];
    rows[0] = blockIdx.x * 4 + rloc;
    rows[1] = rows[0] + 4096;
    int   kk[2];
    int   col[2][2];
    float w[2][2];
    float dval[2];

#pragma unroll
    for (int rr = 0; rr < 2; ++rr) {
        int row = rows[rr];
        int k = cnt[row];
        if (k > STRIDE) k = STRIDE;
        kk[rr] = k;
        int b = row * STRIDE;
        for (int i = lane; i < k; i += 64) sbuf[rloc][rr][i] = ecw[b + i];
    }
    __syncthreads();

#pragma unroll
    for (int rr = 0; rr < 2; ++rr) {
        int row = rows[rr];
        int k = kk[rr];
        float degsum = 0.0f;
        col[rr][0] = 0; col[rr][1] = 0;
        w[rr][0] = 0.0f; w[rr][1] = 0.0f;
        if (lane < k) {
            u64 vi = sbuf[rloc][rr][lane];
            unsigned pi = (unsigned)(vi >> 32);
            col[rr][0] = (int)(pi & 0x1FFFu);
            bool win = true;
            for (int j = 0; j < k; ++j) {      // LDS same-address broadcasts
                unsigned pj = (unsigned)(sbuf[rloc][rr][j] >> 32);
                win = win && !(((pj ^ pi) & 0x1FFFu) == 0u && pj > pi);
            }
            w[rr][0] = win ? __uint_as_float((unsigned)vi) * sig : 0.0f;
            degsum += w[rr][0];
        }
        int i1 = lane + 64;
        if (i1 < k) {
            u64 vi = sbuf[rloc][rr][i1];
            unsigned pi = (unsigned)(vi >> 32);
            col[rr][1] = (int)(pi & 0x1FFFu);
            bool win = true;
            for (int j = 0; j < k; ++j) {
                unsigned pj = (unsigned)(sbuf[rloc][rr][j] >> 32);
                win = win && !(((pj ^ pi) & 0x1FFFu) == 0u && pj > pi);
            }
            w[rr][1] = win ? __uint_as_float((unsigned)vi) * sig : 0.0f;
            degsum += w[rr][1];
        }
        for (int off = 32; off > 0; off >>= 1) degsum += __shfl_down(degsum, off);
        degsum = __shfl(degsum, 0);
        dval[rr] = 1.0f / sqrtf(1.0f + degsum);   // +1: the I diagonal
        if (lane == 0) dinv[row] = dval[rr];
    }
    grid.sync();

    // ---- D: fold dinv[col] into register weights; SpMV1 + combine -> tx1
#pragma unroll
    for (int rr = 0; rr < 2; ++rr) {
        w[rr][0] *= dinv[col[rr][0]];   // w=0 lanes: col=0, harmless load
        w[rr][1] *= dinv[col[rr][1]];
    }
    int sub = lane >> 4;                // 4 edges in flight
    int ch  = (lane & 15) << 2;         // float4 channel offset
#pragma unroll
    for (int rr = 0; rr < 2; ++rr) {
        int row = rows[rr];
        int trips = (kk[rr] + 3) >> 2;  // WAVE-UNIFORM
        float4 acc = {0.f, 0.f, 0.f, 0.f};
        for (int i = 0; i < trips; ++i) {
            int j = (i << 2) + sub;     // j<64 uniform per i
            int cj; float wj;
            if (j < 64) { cj = __shfl(col[rr][0], j);      wj = __shfl(w[rr][0], j); }
            else        { cj = __shfl(col[rr][1], j - 64); wj = __shfl(w[rr][1], j - 64); }
            float4 uv = *(const float4*)(x + (cj << 6) + ch);
            acc.x = fmaf(wj, uv.x, acc.x);
            acc.y = fmaf(wj, uv.y, acc.y);
            acc.z = fmaf(wj, uv.z, acc.z);
            acc.w = fmaf(wj, uv.w, acc.w);
        }
        acc.x += __shfl_xor(acc.x, 16); acc.x += __shfl_xor(acc.x, 32);
        acc.y += __shfl_xor(acc.y, 16); acc.y += __shfl_xor(acc.y, 32);
        acc.z += __shfl_xor(acc.z, 16); acc.z += __shfl_xor(acc.z, 32);
        acc.w += __shfl_xor(acc.w, 16); acc.w += __shfl_xor(acc.w, 32);
        if (sub == 0) {
            float d = dval[rr];
            float dd = d * d;
            int idx = (row << 6) + ch;
            float4 xv = *(const float4*)(x + idx);
            float4 t1;
            t1.x = xv.x - d * acc.x - dd * xv.x;
            t1.y = xv.y - d * acc.y - dd * xv.y;
            t1.z = xv.z - d * acc.z - dd * xv.z;
            t1.w = xv.w - d * acc.w - dd * xv.w;
            *(float4*)(tx1 + idx) = t1;
        }
    }
    grid.sync();

    // ---- E: SpMV2 + combine2 + fused epilogue GEMM (per row)
    float* seg = (float*)&sbuf[rloc][0][0];   // 384 floats = 2 rows x 192
#pragma unroll
    for (int rr = 0; rr < 2; ++rr) {
        int row = rows[rr];
        int trips = (kk[rr] + 3) >> 2;  // WAVE-UNIFORM
        float4 acc = {0.f, 0.f, 0.f, 0.f};
        for (int i = 0; i < trips; ++i) {
            int j = (i << 2) + sub;
            int cj; float wj;
            if (j < 64) { cj = __shfl(col[rr][0], j);      wj = __shfl(w[rr][0], j); }
            else        { cj = __shfl(col[rr][1], j - 64); wj = __shfl(w[rr][1], j - 64); }
            float4 uv = *(const float4*)(tx1 + (cj << 6) + ch);
            acc.x = fmaf(wj, uv.x, acc.x);
            acc.y = fmaf(wj, uv.y, acc.y);
            acc.z = fmaf(wj, uv.z, acc.z);
            acc.w = fmaf(wj, uv.w, acc.w);
        }
        acc.x += __shfl_xor(acc.x, 16); acc.x += __shfl_xor(acc.x, 32);
        acc.y += __shfl_xor(acc.y, 16); acc.y += __shfl_xor(acc.y, 32);
        acc.z += __shfl_xor(acc.z, 16); acc.z += __shfl_xor(acc.z, 32);
        acc.w += __shfl_xor(acc.w, 16); acc.w += __shfl_xor(acc.w, 32);
        if (sub == 0) {
            float d = dval[rr];
            float dd = d * d;
            int idx = (row << 6) + ch;
            float4 xv  = *(const float4*)(x + idx);
            float4 t1v = *(const float4*)(tx1 + idx);
            float4 t2;
            t2.x = 2.0f * (t1v.x - d * acc.x - dd * t1v.x) - xv.x;
            t2.y = 2.0f * (t1v.y - d * acc.y - dd * t1v.y) - xv.y;
            t2.z = 2.0f * (t1v.z - d * acc.z - dd * t1v.z) - xv.z;
            t2.w = 2.0f * (t1v.w - d * acc.w - dd * t1v.w) - xv.w;
            float* xs  = seg + rr * 192;
            float* t1s = xs + CC;
            float* t2s = xs + 2 * CC;
            *(float4*)&xs[ch]  = xv;
            *(float4*)&t1s[ch] = t1v;
            *(float4*)&t2s[ch] = t2;
        }
    }
    __syncthreads();

    const float* W0 = W;
    const float* W1 = W + CC * CC;
    const float* W2 = W + 2 * CC * CC;
#pragma unroll
    for (int rr = 0; rr < 2; ++rr) {
        float* xs  = seg + rr * 192;
        float* t1s = xs + CC;
        float* t2s = xs + 2 * CC;
        float o = bias[lane];
#pragma unroll 16
        for (int m = 0; m < CC; ++m) o = fmaf(xs[m],  W0[(m << 6) + lane], o);
#pragma unroll 16
        for (int m = 0; m < CC; ++m) o = fmaf(t1s[m], W1[(m << 6) + lane], o);
#pragma unroll 16
        for (int m = 0; m < CC; ++m) o = fmaf(t2s[m], W2[(m << 6) + lane], o);
        out[(rows[rr] << 6) + lane] = o;
    }
}

// ====================== FALLBACK (proven R9 pipeline) =======================
__global__ void k_zero(int* __restrict__ cnt) {
    int i = blockIdx.x * blockDim.x + threadIdx.x;
    if (i < NN) cnt[i] = 0;
}

__global__ void k_fill(const int* __restrict__ ei, const float* __restrict__ ew,
                       int* __restrict__ cnt, u64* __restrict__ ecw) {
    int e = blockIdx.x * blockDim.x + threadIdx.x;
    if (e >= EE) return;
    int r = ei[e];
    int c = ei[EE + e];
    int pos = atomicAdd(&cnt[r], 1);
    if (pos < STRIDE) {
        u64 v = ((u64)(((unsigned)e << 13) | (unsigned)c) << 32)
              | (u64)__float_as_uint(ew[e]);
        ecw[r * STRIDE + pos] = v;
    }
}

__global__ __launch_bounds__(256) void k_dedup(
        const int* __restrict__ cnt, u64* __restrict__ ecw,
        const float* __restrict__ adw, float* __restrict__ dinv) {
    __shared__ u64 se[4][STRIDE];
    int tid = threadIdx.x;
    int lane = tid & 63;
    int rloc = tid >> 6;
    int row = blockIdx.x * 4 + rloc;
    int b = row * STRIDE;
    int k = cnt[row];
    if (k > STRIDE) k = STRIDE;
    for (int i = lane; i < k; i += 64) se[rloc][i] = ecw[b + i];
    __syncthreads();

    float sig = 1.0f / (1.0f + expf(-adw[0]));
    float degsum = 0.0f;
    for (int i = lane; i < k; i += 64) {
        u64 vi = se[rloc][i];
        unsigned pi = (unsigned)(vi >> 32);
        unsigned ci = pi & 0x1FFFu;
        bool win = true;
        for (int j = 0; j < k; ++j) {
            unsigned pj = (unsigned)(se[rloc][j] >> 32);
            win = win && !(((pj ^ pi) & 0x1FFFu) == 0u && pj > pi);
        }
        float wi = win ? __uint_as_float((unsigned)vi) * sig : 0.0f;
        ecw[b + i] = ((u64)ci << 32) | (u64)__float_as_uint(wi);
        degsum += wi;
    }
    for (int off = 32; off > 0; off >>= 1) degsum += __shfl_down(degsum, off);
    if (lane == 0) dinv[row] = 1.0f / sqrtf(1.0f + degsum);
}

static __device__ __forceinline__ float4 reg_gather(
        const u64* __restrict__ ecw, const float* __restrict__ dinv,
        const float* __restrict__ src, int b, int k, int lane, int sub, int ch) {
    u64 v0 = (lane < k)      ? ecw[b + lane]      : 0ull;
    u64 v1 = (lane + 64 < k) ? ecw[b + 64 + lane] : 0ull;
    int col0 = (int)(v0 >> 32);
    int col1 = (int)(v1 >> 32);
    float w0 = __uint_as_float((unsigned)v0) * dinv[col0];
    float w1 = __uint_as_float((unsigned)v1) * dinv[col1];

    float4 acc = {0.f, 0.f, 0.f, 0.f};
    int trips = (k + 3) >> 2;            // wave-uniform
#pragma unroll 2
    for (int i = 0; i < trips; ++i) {
        int j = (i << 2) + sub;
        int cj; float wj;
        if (j < 64) { cj = __shfl(col0, j);      wj = __shfl(w0, j); }
        else        { cj = __shfl(col1, j - 64); wj = __shfl(w1, j - 64); }
        float4 uv = *(const float4*)(src + (cj << 6) + ch);
        acc.x = fmaf(wj, uv.x, acc.x);
        acc.y = fmaf(wj, uv.y, acc.y);
        acc.z = fmaf(wj, uv.z, acc.z);
        acc.w = fmaf(wj, uv.w, acc.w);
    }
    acc.x += __shfl_xor(acc.x, 16); acc.x += __shfl_xor(acc.x, 32);
    acc.y += __shfl_xor(acc.y, 16); acc.y += __shfl_xor(acc.y, 32);
    acc.z += __shfl_xor(acc.z, 16); acc.z += __shfl_xor(acc.z, 32);
    acc.w += __shfl_xor(acc.w, 16); acc.w += __shfl_xor(acc.w, 32);
    return acc;
}

__global__ __launch_bounds__(256) void k_spmv1(
        const int* __restrict__ cnt, const u64* __restrict__ ecw,
        const float* __restrict__ dinv, const float* __restrict__ x,
        float* __restrict__ tx1) {
    int tid = threadIdx.x;
    int lane = tid & 63;
    int rloc = tid >> 6;
    int row = blockIdx.x * 4 + rloc;
    int b = row * STRIDE;
    int k = cnt[row];
    if (k > STRIDE) k = STRIDE;
    int sub = lane >> 4;
    int ch = (lane & 15) << 2;
    float4 acc = reg_gather(ecw, dinv, x, b, k, lane, sub, ch);
    if (sub == 0) {
        float d = dinv[row];
        float dd = d * d;
        int idx = (row << 6) + ch;
        float4 xv = *(const float4*)(x + idx);
        float4 t1;
        t1.x = xv.x - d * acc.x - dd * xv.x;
        t1.y = xv.y - d * acc.y - dd * xv.y;
        t1.z = xv.z - d * acc.z - dd * xv.z;
        t1.w = xv.w - d * acc.w - dd * xv.w;
        *(float4*)(tx1 + idx) = t1;
    }
}

__global__ __launch_bounds__(256) void k_spmv2out(
        const int* __restrict__ cnt, const u64* __restrict__ ecw,
        const float* __restrict__ dinv, const float* __restrict__ x,
        const float* __restrict__ tx1, const float* __restrict__ W,
        const float* __restrict__ bias, float* __restrict__ out) {
    __shared__ float xs[4][CC], t1s[4][CC], t2s[4][CC];
    int tid = threadIdx.x;
    int lane = tid & 63;
    int rloc = tid >> 6;
    int row = blockIdx.x * 4 + rloc;
    int b = row * STRIDE;
    int k = cnt[row];
    if (k > STRIDE) k = STRIDE;
    int sub = lane >> 4;
    int ch = (lane & 15) << 2;
    float4 acc = reg_gather(ecw, dinv, tx1, b, k, lane, sub, ch);
    if (sub == 0) {
        float d = dinv[row];
        float dd = d * d;
        int idx = (row << 6) + ch;
        float4 xv = *(const float4*)(x + idx);
        float4 t1v = *(const float4*)(tx1 + idx);
        float4 t2;
        t2.x = 2.0f * (t1v.x - d * acc.x - dd * t1v.x) - xv.x;
        t2.y = 2.0f * (t1v.y - d * acc.y - dd * t1v.y) - xv.y;
        t2.z = 2.0f * (t1v.z - d * acc.z - dd * t1v.z) - xv.z;
        t2.w = 2.0f * (t1v.w - d * acc.w - dd * t1v.w) - xv.w;
        *(float4*)&xs[rloc][ch]  = xv;
        *(float4*)&t1s[rloc][ch] = t1v;
        *(float4*)&t2s[rloc][ch] = t2;
    }
    __syncthreads();

    int c = lane;
    float o = bias[c];
    const float* W0 = W;
    const float* W1 = W + CC * CC;
    const float* W2 = W + 2 * CC * CC;
#pragma unroll 16
    for (int kk = 0; kk < CC; ++kk) o = fmaf(xs[rloc][kk],  W0[(kk << 6) + c], o);
#pragma unroll 16
    for (int kk = 0; kk < CC; ++kk) o = fmaf(t1s[rloc][kk], W1[(kk << 6) + c], o);
#pragma unroll 16
    for (int kk = 0; kk < CC; ++kk) o = fmaf(t2s[rloc][kk], W2[(kk << 6) + c], o);
    out[(row << 6) + c] = o;
}

extern "C" void kernel_launch(void* const* d_in, const int* in_sizes, int n_in,
                              void* d_out, int out_size, void* d_ws, size_t ws_size,
                              hipStream_t stream) {
    const float* x    = (const float*)d_in[0];
    const int*   ei   = (const int*)d_in[1];     // int32
    const float* ew   = (const float*)d_in[2];
    const float* W    = (const float*)d_in[3];   // (3,64,64)
    const float* adw  = (const float*)d_in[4];
    const float* bias = (const float*)d_in[5];
    float*       out  = (float*)d_out;

    // workspace (~8.1 MB)
    char* p = (char*)d_ws;
    auto take = [&](size_t bytes) {
        char* q = p;
        p += (bytes + 255) & ~(size_t)255;
        return q;
    };
    int*   cnt  = (int*)take(NN * sizeof(int));                  // 32 KB
    u64*   ecw  = (u64*)take((size_t)NN * STRIDE * sizeof(u64)); // 6 MB
    float* dinv = (float*)take(NN * sizeof(float));              // 32 KB
    float* tx1  = (float*)take(NN * CC * sizeof(float));         // 2 MB

    void* args[] = {(void*)&x, (void*)&ei, (void*)&ew, (void*)&W, (void*)&adw,
                    (void*)&bias, (void*)&out, (void*)&cnt, (void*)&ecw,
                    (void*)&dinv, (void*)&tx1};
    hipError_t rc = hipLaunchCooperativeKernel((const void*)k_fused, dim3(1024),
                                               dim3(256), args, 0, stream);
    if (rc != hipSuccess) {
        (void)hipGetLastError();   // clear sticky error, use proven pipeline
        const int B = 256;
        hipLaunchKernelGGL(k_zero,     dim3(NN / B), dim3(B), 0, stream, cnt);
        hipLaunchKernelGGL(k_fill,     dim3(EE / B), dim3(B), 0, stream, ei, ew, cnt, ecw);
        hipLaunchKernelGGL(k_dedup,    dim3(NN / 4), dim3(B), 0, stream, cnt, ecw, adw, dinv);
        hipLaunchKernelGGL(k_spmv1,    dim3(NN / 4), dim3(B), 0, stream, cnt, ecw, dinv, x, tx1);
        hipLaunchKernelGGL(k_spmv2out, dim3(NN / 4), dim3(B), 0, stream, cnt, ecw, dinv, x, tx1, W, bias, out);
    }
}

// Round 12
// 114.872 us; speedup vs baseline: 4.3145x; 4.3145x over previous
//
#include <hip/hip_runtime.h>

// Problem constants (fixed by the reference)
#define NN 8192
#define EE 262144
#define CC 64
#define STRIDE 96   // bucket slots/row; Poisson(32) max ~66, P(>96) ~ 1e-19

typedef unsigned long long u64;

// ---- 1. bucket fill: slot = atomicAdd(cnt[r]); one u64 store per edge.
//         hi32 = (e<<13)|col  (max packed == last write, per col), lo32 = ew
//         (cnt is zeroed by a hipMemsetAsync node before this kernel)
__global__ void k_fill(const int* __restrict__ ei, const float* __restrict__ ew,
                       int* __restrict__ cnt, u64* __restrict__ ecw) {
    int e = blockIdx.x * blockDim.x + threadIdx.x;
    if (e >= EE) return;
    int r = ei[e];
    int c = ei[EE + e];
    int pos = atomicAdd(&cnt[r], 1);
    if (pos < STRIDE) {
        u64 v = ((u64)(((unsigned)e << 13) | (unsigned)c) << 32)
              | (u64)__float_as_uint(ew[e]);
        ecw[r * STRIDE + pos] = v;
    }
}

// ---- 2. per-row dedup in LDS (last-write-wins) + weighted degree + dinv.
//         Rewrites slot as (col<<32)|w_final (losers w=0). One wave per row.
__global__ __launch_bounds__(256) void k_dedup(
        const int* __restrict__ cnt, u64* __restrict__ ecw,
        const float* __restrict__ adw, float* __restrict__ dinv) {
    __shared__ u64 se[4][STRIDE];
    int tid = threadIdx.x;
    int lane = tid & 63;
    int rloc = tid >> 6;
    int row = blockIdx.x * 4 + rloc;
    int b = row * STRIDE;
    int k = cnt[row];
    if (k > STRIDE) k = STRIDE;
    for (int i = lane; i < k; i += 64) se[rloc][i] = ecw[b + i];
    __syncthreads();

    float sig = 1.0f / (1.0f + expf(-adw[0]));
    float degsum = 0.0f;
    for (int i = lane; i < k; i += 64) {
        u64 vi = se[rloc][i];
        unsigned pi = (unsigned)(vi >> 32);
        unsigned ci = pi & 0x1FFFu;
        bool win = true;
        for (int j = 0; j < k; ++j) {          // LDS same-address broadcasts
            unsigned pj = (unsigned)(se[rloc][j] >> 32);
            win = win && !(((pj ^ pi) & 0x1FFFu) == 0u && pj > pi);
        }
        float wi = win ? __uint_as_float((unsigned)vi) * sig : 0.0f;
        ecw[b + i] = ((u64)ci << 32) | (u64)__float_as_uint(wi);
        degsum += wi;
    }
    for (int off = 32; off > 0; off >>= 1) degsum += __shfl_down(degsum, off);
    if (lane == 0) dinv[row] = 1.0f / sqrtf(1.0f + degsum);  // +1: I diagonal
}

// ---- register-resident gather core. Each lane owns slots {lane, lane+64}
//      (one coalesced 512B wave-load of ecw), folds dinv[col] once; the gather
//      loop broadcasts (col,w) via shfl so addresses are pure register ALU.
//      Trip count is WAVE-UNIFORM ((k+3)>>2 for every lane) so every __shfl
//      executes with all 64 lanes active (R7/R8 bug: per-lane loop exit masked
//      off shfl source lanes in the tail iteration -> corrupted edge).
//      For j in [k, 4*trips): source lane j holds w=0 (guarded preload), so
//      those iterations contribute exactly 0.
static __device__ __forceinline__ float4 reg_gather(
        const u64* __restrict__ ecw, const float* __restrict__ dinv,
        const float* __restrict__ src, int b, int k, int lane, int sub, int ch) {
    u64 v0 = (lane < k)      ? ecw[b + lane]      : 0ull;
    u64 v1 = (lane + 64 < k) ? ecw[b + 64 + lane] : 0ull;
    int col0 = (int)(v0 >> 32);
    int col1 = (int)(v1 >> 32);
    float w0 = __uint_as_float((unsigned)v0) * dinv[col0];   // 0 for empty slots
    float w1 = __uint_as_float((unsigned)v1) * dinv[col1];

    float4 acc = {0.f, 0.f, 0.f, 0.f};
    int trips = (k + 3) >> 2;            // wave-uniform
#pragma unroll 2
    for (int i = 0; i < trips; ++i) {
        int j = (i << 2) + sub;          // j < 64 test is uniform per i
        int cj; float wj;
        if (j < 64) { cj = __shfl(col0, j);      wj = __shfl(w0, j); }
        else        { cj = __shfl(col1, j - 64); wj = __shfl(w1, j - 64); }
        float4 uv = *(const float4*)(src + (cj << 6) + ch);
        acc.x = fmaf(wj, uv.x, acc.x);
        acc.y = fmaf(wj, uv.y, acc.y);
        acc.z = fmaf(wj, uv.z, acc.z);
        acc.w = fmaf(wj, uv.w, acc.w);
    }
    acc.x += __shfl_xor(acc.x, 16); acc.x += __shfl_xor(acc.x, 32);
    acc.y += __shfl_xor(acc.y, 16); acc.y += __shfl_xor(acc.y, 32);
    acc.z += __shfl_xor(acc.z, 16); acc.z += __shfl_xor(acc.z, 32);
    acc.w += __shfl_xor(acc.w, 16); acc.w += __shfl_xor(acc.w, 32);
    return acc;
}

// ---- 3. SpMV1 + combine: tx1 = x - d*acc - d^2*x   (one wave per row)
__global__ __launch_bounds__(256) void k_spmv1(
        const int* __restrict__ cnt, const u64* __restrict__ ecw,
        const float* __restrict__ dinv, const float* __restrict__ x,
        float* __restrict__ tx1) {
    int tid = threadIdx.x;
    int lane = tid & 63;
    int rloc = tid >> 6;
    int row = blockIdx.x * 4 + rloc;
    int b = row * STRIDE;
    int k = cnt[row];
    if (k > STRIDE) k = STRIDE;
    int sub = lane >> 4;
    int ch = (lane & 15) << 2;
    float4 acc = reg_gather(ecw, dinv, x, b, k, lane, sub, ch);
    if (sub == 0) {
        float d = dinv[row];
        float dd = d * d;
        int idx = (row << 6) + ch;
        float4 xv = *(const float4*)(x + idx);
        float4 t1;
        t1.x = xv.x - d * acc.x - dd * xv.x;
        t1.y = xv.y - d * acc.y - dd * xv.y;
        t1.z = xv.z - d * acc.z - dd * xv.z;
        t1.w = xv.w - d * acc.w - dd * xv.w;
        *(float4*)(tx1 + idx) = t1;
    }
}

// ---- 4. SpMV2 + combine2 + fused epilogue GEMM
//         tx2 = 2*(tx1 - d*acc - d^2*tx1) - x ; out = x@W0+tx1@W1+tx2@W2+bias
__global__ __launch_bounds__(256) void k_spmv2out(
        const int* __restrict__ cnt, const u64* __restrict__ ecw,
        const float* __restrict__ dinv, const float* __restrict__ x,
        const float* __restrict__ tx1, const float* __restrict__ W,
        const float* __restrict__ bias, float* __restrict__ out) {
    __shared__ float xs[4][CC], t1s[4][CC], t2s[4][CC];
    int tid = threadIdx.x;
    int lane = tid & 63;
    int rloc = tid >> 6;
    int row = blockIdx.x * 4 + rloc;
    int b = row * STRIDE;
    int k = cnt[row];
    if (k > STRIDE) k = STRIDE;
    int sub = lane >> 4;
    int ch = (lane & 15) << 2;
    float4 acc = reg_gather(ecw, dinv, tx1, b, k, lane, sub, ch);
    if (sub == 0) {
        float d = dinv[row];
        float dd = d * d;
        int idx = (row << 6) + ch;
        float4 xv = *(const float4*)(x + idx);
        float4 t1v = *(const float4*)(tx1 + idx);
        float4 t2;
        t2.x = 2.0f * (t1v.x - d * acc.x - dd * t1v.x) - xv.x;
        t2.y = 2.0f * (t1v.y - d * acc.y - dd * t1v.y) - xv.y;
        t2.z = 2.0f * (t1v.z - d * acc.z - dd * t1v.z) - xv.z;
        t2.w = 2.0f * (t1v.w - d * acc.w - dd * t1v.w) - xv.w;
        *(float4*)&xs[rloc][ch]  = xv;
        *(float4*)&t1s[rloc][ch] = t1v;
        *(float4*)&t2s[rloc][ch] = t2;
    }
    __syncthreads();

    int c = lane;
    float o = bias[c];
    const float* W0 = W;
    const float* W1 = W + CC * CC;
    const float* W2 = W + 2 * CC * CC;
#pragma unroll 16
    for (int kk = 0; kk < CC; ++kk) o = fmaf(xs[rloc][kk],  W0[(kk << 6) + c], o);
#pragma unroll 16
    for (int kk = 0; kk < CC; ++kk) o = fmaf(t1s[rloc][kk], W1[(kk << 6) + c], o);
#pragma unroll 16
    for (int kk = 0; kk < CC; ++kk) o = fmaf(t2s[rloc][kk], W2[(kk << 6) + c], o);
    out[(row << 6) + c] = o;
}

extern "C" void kernel_launch(void* const* d_in, const int* in_sizes, int n_in,
                              void* d_out, int out_size, void* d_ws, size_t ws_size,
                              hipStream_t stream) {
    const float* x    = (const float*)d_in[0];
    const int*   ei   = (const int*)d_in[1];     // int32
    const float* ew   = (const float*)d_in[2];
    const float* W    = (const float*)d_in[3];   // (3,64,64)
    const float* adw  = (const float*)d_in[4];
    const float* bias = (const float*)d_in[5];
    float*       out  = (float*)d_out;

    // workspace (~8.1 MB)
    char* p = (char*)d_ws;
    auto take = [&](size_t bytes) {
        char* q = p;
        p += (bytes + 255) & ~(size_t)255;
        return q;
    };
    int*   cnt  = (int*)take(NN * sizeof(int));                  // 32 KB
    u64*   ecw  = (u64*)take((size_t)NN * STRIDE * sizeof(u64)); // 6 MB
    float* dinv = (float*)take(NN * sizeof(float));              // 32 KB
    float* tx1  = (float*)take(NN * CC * sizeof(float));         // 2 MB

    const int B = 256;
    // zero cnt as a graph memset node (replaces the k_zero kernel launch)
    hipMemsetAsync(cnt, 0, NN * sizeof(int), stream);
    hipLaunchKernelGGL(k_fill,     dim3(EE / B), dim3(B), 0, stream, ei, ew, cnt, ecw);
    hipLaunchKernelGGL(k_dedup,    dim3(NN / 4), dim3(B), 0, stream, cnt, ecw, adw, dinv);
    hipLaunchKernelGGL(k_spmv1,    dim3(NN / 4), dim3(B), 0, stream, cnt, ecw, dinv, x, tx1);
    hipLaunchKernelGGL(k_spmv2out, dim3(NN / 4), dim3(B), 0, stream, cnt, ecw, dinv, x, tx1, W, bias, out);
}